// Round 1
// baseline (1852.234 us; speedup 1.0000x reference)
//
#include <hip/hip_runtime.h>
#include <hip/hip_bf16.h>
#include <cstdint>
#include <cstddef>

#define BATCH 2
#define SEQ 2048
#define DMODEL 1024
#define DIN 2048
#define NH 32
#define HEADDIM 64
#define DSTATE 64
#define DCONV 4
#define CONV_DIM (DIN + 2 * DSTATE)          // 2176
#define DPROJ (2 * DIN + 2 * DSTATE + NH)    // 4256
#define MLP_INNER 4096
#define TOKENS (BATCH * SEQ)                 // 4096
#define EPS 1e-5f

typedef __attribute__((ext_vector_type(8))) short short8;
typedef __attribute__((ext_vector_type(8))) __bf16 bf16x8;
typedef __attribute__((ext_vector_type(4))) float f32x4;

__device__ inline short f2bf(float f) {
    unsigned u = __builtin_bit_cast(unsigned, f);
    u = (u + 0x7FFFu + ((u >> 16) & 1u)) >> 16;
    return (short)u;
}
__device__ inline float silu_f(float x) { return x / (1.f + __expf(-x)); }

__device__ inline bf16x8 ld_frag(const short* p) {
    short8 s = *(const short8*)p;
    return __builtin_bit_cast(bf16x8, s);
}

// ---------------- Generic bf16-MFMA GEMM: C = epilogue(A @ B) ----------------
// A: M x K (f32, row-major), B: K x N (f32, row-major), C: M x N (f32)
// MODE 0: C = AB;  1: C = silu(AB + bias);  2: C = AB + bias + res;  3: C = AB + res
// Block tile 128x128, BK=32, 256 threads (4 waves in 2x2 of 64x64 wave tiles).
template <int MODE>
__global__ __launch_bounds__(256, 2) void gemm_kernel(
    const float* __restrict__ A, const float* __restrict__ B,
    float* __restrict__ C, const float* __restrict__ bias,
    const float* __restrict__ res, int M, int N, int K)
{
    const int tid  = threadIdx.x;
    const int wid  = tid >> 6;
    const int lane = tid & 63;
    const int lm   = lane & 15;   // row/col within 16
    const int lg   = lane >> 4;   // k-quad / row-quad
    const int m0   = blockIdx.y * 128;
    const int n0   = blockIdx.x * 128;

    __shared__ short Alds[128 * 40];  // [row][k], stride 40 (pad) -> 16B-aligned rows
    __shared__ short Blds[128 * 40];  // [n][k] transposed, stride 40

    f32x4 acc[4][4];
#pragma unroll
    for (int i = 0; i < 4; ++i)
#pragma unroll
        for (int j = 0; j < 4; ++j) acc[i][j] = {0.f, 0.f, 0.f, 0.f};

    const int wm = (wid >> 1) * 64;
    const int wn = (wid & 1) * 64;

    const int arow = tid >> 3;        // 0..31
    const int acol = (tid & 7) * 4;   // 0..28
    const int bk   = tid >> 5;        // 0..7
    const int bn   = (tid & 31) * 4;  // 0..124

    for (int kt = 0; kt < K; kt += 32) {
        __syncthreads();
        // stage A tile (128 x 32)
#pragma unroll
        for (int r = 0; r < 4; ++r) {
            int row = arow + r * 32;
            f32x4 v = *(const f32x4*)(A + (size_t)(m0 + row) * K + kt + acol);
            short4 pk;
            pk.x = f2bf(v.x); pk.y = f2bf(v.y); pk.z = f2bf(v.z); pk.w = f2bf(v.w);
            *(short4*)&Alds[row * 40 + acol] = pk;
        }
        // stage B tile (32 x 128), transposed into LDS
#pragma unroll
        for (int r = 0; r < 4; ++r) {
            int k = bk + r * 8;
            f32x4 v = {0.f, 0.f, 0.f, 0.f};
            if (n0 + bn < N) v = *(const f32x4*)(B + (size_t)(kt + k) * N + n0 + bn);
            Blds[(bn + 0) * 40 + k] = f2bf(v.x);
            Blds[(bn + 1) * 40 + k] = f2bf(v.y);
            Blds[(bn + 2) * 40 + k] = f2bf(v.z);
            Blds[(bn + 3) * 40 + k] = f2bf(v.w);
        }
        __syncthreads();

        bf16x8 af[4], bfr[4];
#pragma unroll
        for (int i = 0; i < 4; ++i)
            af[i] = ld_frag(&Alds[(wm + i * 16 + lm) * 40 + lg * 8]);
#pragma unroll
        for (int j = 0; j < 4; ++j)
            bfr[j] = ld_frag(&Blds[(wn + j * 16 + lm) * 40 + lg * 8]);
#pragma unroll
        for (int i = 0; i < 4; ++i)
#pragma unroll
            for (int j = 0; j < 4; ++j)
                acc[i][j] = __builtin_amdgcn_mfma_f32_16x16x32_bf16(af[i], bfr[j], acc[i][j], 0, 0, 0);
    }

    // epilogue: C/D layout col=lane&15, row=(lane>>4)*4+reg
#pragma unroll
    for (int i = 0; i < 4; ++i) {
#pragma unroll
        for (int j = 0; j < 4; ++j) {
            int col = n0 + wn + j * 16 + lm;
            if (col >= N) continue;
            float bv = (MODE == 1 || MODE == 2) ? bias[col] : 0.f;
#pragma unroll
            for (int r = 0; r < 4; ++r) {
                int row = m0 + wm + i * 16 + lg * 4 + r;
                float v = acc[i][j][r];
                if (MODE == 1) v = silu_f(v + bv);
                if (MODE == 2) v = v + bv + res[(size_t)row * N + col];
                if (MODE == 3) v = v + res[(size_t)row * N + col];
                C[(size_t)row * N + col] = v;
            }
        }
    }
}

// ---------------- depthwise causal conv (k=4) + bias + silu ----------------
__global__ __launch_bounds__(256) void conv_kernel(
    const float* __restrict__ zx, const float* __restrict__ cw,
    const float* __restrict__ cb, float* __restrict__ xBCc)
{
    int c4 = blockIdx.y * 256 + threadIdx.x;
    if (c4 >= CONV_DIM / 4) return;
    int m = blockIdx.x;
    int l = m & (SEQ - 1);
    int c = c4 * 4;
    const float* base = zx + (size_t)m * DPROJ + DIN + c;
    f32x4 acc = {0.f, 0.f, 0.f, 0.f};
#pragma unroll
    for (int j = 0; j < DCONV; ++j) {
        if (l - 3 + j < 0) continue;
        f32x4 xv = *(const f32x4*)(base + (ptrdiff_t)(j - 3) * DPROJ);
        acc.x += xv.x * cw[(c + 0) * DCONV + j];
        acc.y += xv.y * cw[(c + 1) * DCONV + j];
        acc.z += xv.z * cw[(c + 2) * DCONV + j];
        acc.w += xv.w * cw[(c + 3) * DCONV + j];
    }
    f32x4 o;
    o.x = silu_f(acc.x + cb[c + 0]);
    o.y = silu_f(acc.y + cb[c + 1]);
    o.z = silu_f(acc.z + cb[c + 2]);
    o.w = silu_f(acc.w + cb[c + 3]);
    *(f32x4*)(xBCc + (size_t)m * CONV_DIM + c) = o;
}

// ---------------- dt = softplus(dt_raw + bias), dA = exp(dt * -exp(A_log)) ----------------
__global__ __launch_bounds__(256) void dt_kernel(
    const float* __restrict__ zx, const float* __restrict__ dt_bias,
    const float* __restrict__ A_log, float* __restrict__ dtb, float* __restrict__ dAb)
{
    int idx = blockIdx.x * 256 + threadIdx.x;
    if (idx >= TOKENS * NH) return;
    int hh = idx & (NH - 1);
    int m  = idx >> 5;
    float v  = zx[(size_t)m * DPROJ + DIN + CONV_DIM + hh] + dt_bias[hh];
    float dt = (v > 20.f) ? v : log1pf(__expf(v));
    dtb[idx] = dt;
    dAb[idx] = __expf(-__expf(A_log[hh]) * dt);
}

// ---------------- sequential SSM scan ----------------
// grid: 256 blocks = (b,h) x 4 p-groups; 256 threads: pl=t>>4 (16 p), lane16=t&15 (4 n each)
__global__ __launch_bounds__(256) void scan_kernel(
    const float* __restrict__ xBCc, const float* __restrict__ dtb,
    const float* __restrict__ dAb, const float* __restrict__ Dp,
    float* __restrict__ y)
{
    int bh = blockIdx.x >> 2;
    int pg = blockIdx.x & 3;
    int b  = bh >> 5;
    int h  = bh & 31;
    int t  = threadIdx.x;
    int pl = t >> 4;
    int p  = pg * 16 + pl;
    int lane16 = t & 15;
    int n0 = lane16 * 4;

    const float* xrow = xBCc + (size_t)b * SEQ * CONV_DIM;
    const float* dtp  = dtb + (size_t)b * SEQ * NH + h;
    const float* dAp  = dAb + (size_t)b * SEQ * NH + h;
    float Dh = Dp[h];
    float* yp = y + (size_t)b * SEQ * DIN + h * HEADDIM + p;

    f32x4 hs = {0.f, 0.f, 0.f, 0.f};

    f32x4 B0, C0, B1, C1;
    float x0, a0, d0, x1, a1, d1;
    {
        const float* r0 = xrow;
        B0 = *(const f32x4*)(r0 + DIN + n0);
        C0 = *(const f32x4*)(r0 + DIN + DSTATE + n0);
        x0 = r0[h * HEADDIM + p]; a0 = dAp[0]; d0 = dtp[0];
        const float* r1 = xrow + (size_t)CONV_DIM;
        B1 = *(const f32x4*)(r1 + DIN + n0);
        C1 = *(const f32x4*)(r1 + DIN + DSTATE + n0);
        x1 = r1[h * HEADDIM + p]; a1 = dAp[NH]; d1 = dtp[NH];
    }

    for (int l = 0; l < SEQ; l += 2) {
        // ---- step l (consume set0, prefetch l+2) ----
        {
            f32x4 Bc = B0, Cc = C0; float xs = x0, dA = a0, dtv = d0;
            int ln = l + 2; if (ln > SEQ - 1) ln = SEQ - 1;
            const float* r = xrow + (size_t)ln * CONV_DIM;
            B0 = *(const f32x4*)(r + DIN + n0);
            C0 = *(const f32x4*)(r + DIN + DSTATE + n0);
            x0 = r[h * HEADDIM + p]; a0 = dAp[(size_t)ln * NH]; d0 = dtp[(size_t)ln * NH];

            float dtx = dtv * xs;
            hs.x = dA * hs.x + dtx * Bc.x;
            hs.y = dA * hs.y + dtx * Bc.y;
            hs.z = dA * hs.z + dtx * Bc.z;
            hs.w = dA * hs.w + dtx * Bc.w;
            float part = hs.x * Cc.x + hs.y * Cc.y + hs.z * Cc.z + hs.w * Cc.w;
            part += __shfl_xor(part, 1);
            part += __shfl_xor(part, 2);
            part += __shfl_xor(part, 4);
            part += __shfl_xor(part, 8);
            if (lane16 == 0) yp[(size_t)l * DIN] = part + Dh * xs;
        }
        // ---- step l+1 (consume set1, prefetch l+3) ----
        {
            f32x4 Bc = B1, Cc = C1; float xs = x1, dA = a1, dtv = d1;
            int ln = l + 3; if (ln > SEQ - 1) ln = SEQ - 1;
            const float* r = xrow + (size_t)ln * CONV_DIM;
            B1 = *(const f32x4*)(r + DIN + n0);
            C1 = *(const f32x4*)(r + DIN + DSTATE + n0);
            x1 = r[h * HEADDIM + p]; a1 = dAp[(size_t)ln * NH]; d1 = dtp[(size_t)ln * NH];

            float dtx = dtv * xs;
            hs.x = dA * hs.x + dtx * Bc.x;
            hs.y = dA * hs.y + dtx * Bc.y;
            hs.z = dA * hs.z + dtx * Bc.z;
            hs.w = dA * hs.w + dtx * Bc.w;
            float part = hs.x * Cc.x + hs.y * Cc.y + hs.z * Cc.z + hs.w * Cc.w;
            part += __shfl_xor(part, 1);
            part += __shfl_xor(part, 2);
            part += __shfl_xor(part, 4);
            part += __shfl_xor(part, 8);
            if (lane16 == 0) yp[(size_t)(l + 1) * DIN] = part + Dh * xs;
        }
    }
}

// ---------------- y = rmsnorm(y * silu(z), norm_w), in-place over y ----------------
__global__ __launch_bounds__(256) void norm1_kernel(
    const float* __restrict__ zx, float* __restrict__ y, const float* __restrict__ w)
{
    int m = blockIdx.x;
    int t = threadIdx.x;
    const float* zr = zx + (size_t)m * DPROJ;
    float* yr = y + (size_t)m * DIN;
    float vals[8];
    float ss = 0.f;
#pragma unroll
    for (int j = 0; j < 8; ++j) {
        int i = j * 256 + t;
        float v = yr[i] * silu_f(zr[i]);
        vals[j] = v;
        ss += v * v;
    }
#pragma unroll
    for (int o = 32; o >= 1; o >>= 1) ss += __shfl_xor(ss, o);
    __shared__ float wsum[4];
    if ((t & 63) == 0) wsum[t >> 6] = ss;
    __syncthreads();
    float tot = wsum[0] + wsum[1] + wsum[2] + wsum[3];
    float scale = rsqrtf(tot / (float)DIN + EPS);
#pragma unroll
    for (int j = 0; j < 8; ++j) {
        int i = j * 256 + t;
        yr[i] = vals[j] * scale * w[i];
    }
}

// ---------------- hn = rmsnorm(h, rms_w) ----------------
__global__ __launch_bounds__(256) void norm2_kernel(
    const float* __restrict__ hb, float* __restrict__ hn, const float* __restrict__ w)
{
    int m = blockIdx.x;
    int t = threadIdx.x;
    const float* hr = hb + (size_t)m * DMODEL;
    float vals[4];
    float ss = 0.f;
#pragma unroll
    for (int j = 0; j < 4; ++j) {
        int i = j * 256 + t;
        float v = hr[i];
        vals[j] = v;
        ss += v * v;
    }
#pragma unroll
    for (int o = 32; o >= 1; o >>= 1) ss += __shfl_xor(ss, o);
    __shared__ float wsum[4];
    if ((t & 63) == 0) wsum[t >> 6] = ss;
    __syncthreads();
    float tot = wsum[0] + wsum[1] + wsum[2] + wsum[3];
    float scale = rsqrtf(tot / (float)DMODEL + EPS);
#pragma unroll
    for (int j = 0; j < 4; ++j) {
        int i = j * 256 + t;
        hn[(size_t)m * DMODEL + i] = vals[j] * scale * w[i];
    }
}

extern "C" void kernel_launch(void* const* d_in, const int* in_sizes, int n_in,
                              void* d_out, int out_size, void* d_ws, size_t ws_size,
                              hipStream_t stream) {
    const float* x       = (const float*)d_in[0];
    const float* W_in    = (const float*)d_in[1];
    const float* conv_w  = (const float*)d_in[2];
    const float* conv_b  = (const float*)d_in[3];
    const float* dt_bias = (const float*)d_in[4];
    const float* A_log   = (const float*)d_in[5];
    const float* D_param = (const float*)d_in[6];
    const float* norm_w  = (const float*)d_in[7];
    const float* W_out   = (const float*)d_in[8];
    const float* rms_w   = (const float*)d_in[9];
    const float* mlp_w1  = (const float*)d_in[10];
    const float* mlp_b1  = (const float*)d_in[11];
    const float* mlp_w2  = (const float*)d_in[12];
    const float* mlp_b2  = (const float*)d_in[13];
    float* out = (float*)d_out;

    float* ws    = (float*)d_ws;
    float* zx    = ws;                              // TOKENS*DPROJ   = 17,432,576
    float* xBCc  = zx + (size_t)TOKENS * DPROJ;     // TOKENS*CONV_DIM =  8,912,896
    float* dtb   = xBCc + (size_t)TOKENS * CONV_DIM;// TOKENS*NH       =    131,072
    float* dAb   = dtb + (size_t)TOKENS * NH;
    float* ybuf  = dAb + (size_t)TOKENS * NH;       // TOKENS*DIN      =  8,388,608
    float* hbuf  = ybuf + (size_t)TOKENS * DIN;     // TOKENS*DMODEL   =  4,194,304
    float* hnbuf = hbuf + (size_t)TOKENS * DMODEL;  // TOKENS*DMODEL
    float* mid   = zx;  // reuse zx region for MLP intermediate (TOKENS*MLP_INNER fits)

    dim3 blk(256);

    // 1. zxbcdt = x @ W_in
    gemm_kernel<0><<<dim3((DPROJ + 127) / 128, TOKENS / 128), blk, 0, stream>>>(
        x, W_in, zx, nullptr, nullptr, TOKENS, DPROJ, DMODEL);
    // 2. conv + bias + silu
    conv_kernel<<<dim3(TOKENS, (CONV_DIM / 4 + 255) / 256), blk, 0, stream>>>(
        zx, conv_w, conv_b, xBCc);
    // 3. dt / dA
    dt_kernel<<<dim3(TOKENS * NH / 256), blk, 0, stream>>>(zx, dt_bias, A_log, dtb, dAb);
    // 4. sequential scan -> y (+ D*xs)
    scan_kernel<<<dim3(BATCH * NH * 4), blk, 0, stream>>>(xBCc, dtb, dAb, D_param, ybuf);
    // 5. y = rmsnorm(y * silu(z)) (in place)
    norm1_kernel<<<dim3(TOKENS), blk, 0, stream>>>(zx, ybuf, norm_w);
    // 6. h = x + y @ W_out
    gemm_kernel<3><<<dim3(DMODEL / 128, TOKENS / 128), blk, 0, stream>>>(
        ybuf, W_out, hbuf, nullptr, x, TOKENS, DMODEL, DIN);
    // 7. hn = rmsnorm(h)
    norm2_kernel<<<dim3(TOKENS), blk, 0, stream>>>(hbuf, hnbuf, rms_w);
    // 8. mid = silu(hn @ mlp_w1 + b1)
    gemm_kernel<1><<<dim3(MLP_INNER / 128, TOKENS / 128), blk, 0, stream>>>(
        hnbuf, mlp_w1, mid, mlp_b1, nullptr, TOKENS, MLP_INNER, DMODEL);
    // 9. out = h + mid @ mlp_w2 + b2
    gemm_kernel<2><<<dim3(DMODEL / 128, TOKENS / 128), blk, 0, stream>>>(
        mid, mlp_w2, out, mlp_b2, hbuf, TOKENS, DMODEL, MLP_INNER);
}

// Round 2
// 1215.639 us; speedup vs baseline: 1.5237x; 1.5237x over previous
//
#include <hip/hip_runtime.h>
#include <hip/hip_bf16.h>
#include <cstdint>
#include <cstddef>

#define BATCH 2
#define SEQ 2048
#define DMODEL 1024
#define DIN 2048
#define NH 32
#define HEADDIM 64
#define DSTATE 64
#define DCONV 4
#define CONV_DIM (DIN + 2 * DSTATE)          // 2176
#define DPROJ (2 * DIN + 2 * DSTATE + NH)    // 4256
#define MLP_INNER 4096
#define TOKENS (BATCH * SEQ)                 // 4096
#define EPS 1e-5f
#define Q 64
#define NCHUNK (SEQ / Q)                     // 32
#define NCH (BATCH * NCHUNK * NH)            // 2048 chunk-heads
#define LSTR 72                              // LDS row stride (shorts), 144B rows

typedef __attribute__((ext_vector_type(8))) short short8;
typedef __attribute__((ext_vector_type(8))) __bf16 bf16x8;
typedef __attribute__((ext_vector_type(4))) float f32x4;

__device__ inline short f2bf(float f) {
    unsigned u = __builtin_bit_cast(unsigned, f);
    u = (u + 0x7FFFu + ((u >> 16) & 1u)) >> 16;
    return (short)u;
}
__device__ inline float bf2f(short s) {
    unsigned u = ((unsigned)(unsigned short)s) << 16;
    return __builtin_bit_cast(float, u);
}
__device__ inline float silu_f(float x) { return x / (1.f + __expf(-x)); }

__device__ inline bf16x8 ld_frag(const short* p) {
    short8 s = *(const short8*)p;
    return __builtin_bit_cast(bf16x8, s);
}

// ---------------- Generic bf16-MFMA GEMM (unchanged from R1) ----------------
// MODE 0: C = AB;  1: C = silu(AB + bias);  2: C = AB + bias + res;  3: C = AB + res
template <int MODE>
__global__ __launch_bounds__(256, 2) void gemm_kernel(
    const float* __restrict__ A, const float* __restrict__ B,
    float* __restrict__ C, const float* __restrict__ bias,
    const float* __restrict__ res, int M, int N, int K)
{
    const int tid  = threadIdx.x;
    const int wid  = tid >> 6;
    const int lane = tid & 63;
    const int lm   = lane & 15;
    const int lg   = lane >> 4;
    const int m0   = blockIdx.y * 128;
    const int n0   = blockIdx.x * 128;

    __shared__ short Alds[128 * 40];
    __shared__ short Blds[128 * 40];

    f32x4 acc[4][4];
#pragma unroll
    for (int i = 0; i < 4; ++i)
#pragma unroll
        for (int j = 0; j < 4; ++j) acc[i][j] = {0.f, 0.f, 0.f, 0.f};

    const int wm = (wid >> 1) * 64;
    const int wn = (wid & 1) * 64;

    const int arow = tid >> 3;
    const int acol = (tid & 7) * 4;
    const int bk   = tid >> 5;
    const int bn   = (tid & 31) * 4;

    for (int kt = 0; kt < K; kt += 32) {
        __syncthreads();
#pragma unroll
        for (int r = 0; r < 4; ++r) {
            int row = arow + r * 32;
            f32x4 v = *(const f32x4*)(A + (size_t)(m0 + row) * K + kt + acol);
            short4 pk;
            pk.x = f2bf(v.x); pk.y = f2bf(v.y); pk.z = f2bf(v.z); pk.w = f2bf(v.w);
            *(short4*)&Alds[row * 40 + acol] = pk;
        }
#pragma unroll
        for (int r = 0; r < 4; ++r) {
            int k = bk + r * 8;
            f32x4 v = {0.f, 0.f, 0.f, 0.f};
            if (n0 + bn < N) v = *(const f32x4*)(B + (size_t)(kt + k) * N + n0 + bn);
            Blds[(bn + 0) * 40 + k] = f2bf(v.x);
            Blds[(bn + 1) * 40 + k] = f2bf(v.y);
            Blds[(bn + 2) * 40 + k] = f2bf(v.z);
            Blds[(bn + 3) * 40 + k] = f2bf(v.w);
        }
        __syncthreads();

        bf16x8 af[4], bfr[4];
#pragma unroll
        for (int i = 0; i < 4; ++i)
            af[i] = ld_frag(&Alds[(wm + i * 16 + lm) * 40 + lg * 8]);
#pragma unroll
        for (int j = 0; j < 4; ++j)
            bfr[j] = ld_frag(&Blds[(wn + j * 16 + lm) * 40 + lg * 8]);
#pragma unroll
        for (int i = 0; i < 4; ++i)
#pragma unroll
            for (int j = 0; j < 4; ++j)
                acc[i][j] = __builtin_amdgcn_mfma_f32_16x16x32_bf16(af[i], bfr[j], acc[i][j], 0, 0, 0);
    }

#pragma unroll
    for (int i = 0; i < 4; ++i) {
#pragma unroll
        for (int j = 0; j < 4; ++j) {
            int col = n0 + wn + j * 16 + lm;
            if (col >= N) continue;
            float bv = (MODE == 1 || MODE == 2) ? bias[col] : 0.f;
#pragma unroll
            for (int r = 0; r < 4; ++r) {
                int row = m0 + wm + i * 16 + lg * 4 + r;
                float v = acc[i][j][r];
                if (MODE == 1) v = silu_f(v + bv);
                if (MODE == 2) v = v + bv + res[(size_t)row * N + col];
                if (MODE == 3) v = v + res[(size_t)row * N + col];
                C[(size_t)row * N + col] = v;
            }
        }
    }
}

// ---------------- depthwise causal conv (k=4) + bias + silu ----------------
__global__ __launch_bounds__(256) void conv_kernel(
    const float* __restrict__ zx, const float* __restrict__ cw,
    const float* __restrict__ cb, float* __restrict__ xBCc)
{
    int c4 = blockIdx.y * 256 + threadIdx.x;
    if (c4 >= CONV_DIM / 4) return;
    int m = blockIdx.x;
    int l = m & (SEQ - 1);
    int c = c4 * 4;
    const float* base = zx + (size_t)m * DPROJ + DIN + c;
    f32x4 acc = {0.f, 0.f, 0.f, 0.f};
#pragma unroll
    for (int j = 0; j < DCONV; ++j) {
        if (l - 3 + j < 0) continue;
        f32x4 xv = *(const f32x4*)(base + (ptrdiff_t)(j - 3) * DPROJ);
        acc.x += xv.x * cw[(c + 0) * DCONV + j];
        acc.y += xv.y * cw[(c + 1) * DCONV + j];
        acc.z += xv.z * cw[(c + 2) * DCONV + j];
        acc.w += xv.w * cw[(c + 3) * DCONV + j];
    }
    f32x4 o;
    o.x = silu_f(acc.x + cb[c + 0]);
    o.y = silu_f(acc.y + cb[c + 1]);
    o.z = silu_f(acc.z + cb[c + 2]);
    o.w = silu_f(acc.w + cb[c + 3]);
    *(f32x4*)(xBCc + (size_t)m * CONV_DIM + c) = o;
}

// ---------------- dt = softplus(dt_raw + bias); ldA = A * dt ----------------
__global__ __launch_bounds__(256) void dt_kernel(
    const float* __restrict__ zx, const float* __restrict__ dt_bias,
    const float* __restrict__ A_log, float* __restrict__ dtb, float* __restrict__ ldab)
{
    int idx = blockIdx.x * 256 + threadIdx.x;
    if (idx >= TOKENS * NH) return;
    int hh = idx & (NH - 1);
    int m  = idx >> 5;
    float v  = zx[(size_t)m * DPROJ + DIN + CONV_DIM + hh] + dt_bias[hh];
    float dt = (v > 20.f) ? v : log1pf(__expf(v));
    dtb[idx]  = dt;
    ldab[idx] = -__expf(A_log[hh]) * dt;   // dt * A, A = -exp(A_log)
}

// ---------------- P1: per chunk-head intra-chunk SSD ----------------
// grid = 2048 blocks: bid = ((b*NCHUNK + c)*NH + h); 256 threads (4 waves)
// outputs: ybuf (intra y), Sbuf [bid][n][p], cumdecay [bid][t] = exp(Lc_t)
__global__ __launch_bounds__(256) void chunk_kernel(
    const float* __restrict__ xBCc, const float* __restrict__ dtb,
    const float* __restrict__ ldab, float* __restrict__ ybuf,
    float* __restrict__ Sbuf, float* __restrict__ cumdecay)
{
    int bid = blockIdx.x;
    int h = bid & 31, c = (bid >> 5) & 31, b = bid >> 10;
    int m0 = b * SEQ + c * Q;
    int tid = threadIdx.x;
    int wid = tid >> 6, lane = tid & 63, lm = lane & 15, lg = lane >> 4;

    __shared__ short Cc[64 * LSTR];   // [t][n]
    __shared__ short Bb[64 * LSTR];   // [s][n]
    __shared__ short BwT[64 * LSTR];  // [n][s] decay-weighted
    __shared__ short Xt[64 * LSTR];   // [p][s] dt-weighted
    __shared__ short Mm[64 * LSTR];   // [t][s]
    __shared__ float Lc[64], dtv[64];

    // wave0: load dt, ldA; inclusive prefix sum of ldA
    if (tid < 64) {
        int s = tid;
        size_t ix = (size_t)(m0 + s) * NH + h;
        float ld = ldab[ix];
        float dt = dtb[ix];
        float v = ld;
#pragma unroll
        for (int off = 1; off < 64; off <<= 1) {
            float o = __shfl_up(v, off);
            if (s >= off) v += o;
        }
        Lc[s] = v;
        dtv[s] = dt;
        cumdecay[(size_t)bid * 64 + s] = __expf(v);
    }
    // stage Cc, Bb (f32 -> bf16)
    {
        int row = tid >> 2, c0 = (tid & 3) * 16;
        const float* pB = xBCc + (size_t)(m0 + row) * CONV_DIM + DIN;
#pragma unroll
        for (int u = 0; u < 4; ++u) {
            f32x4 vb = *(const f32x4*)(pB + c0 + 4 * u);
            f32x4 vc = *(const f32x4*)(pB + DSTATE + c0 + 4 * u);
            short4 sb, sc;
            sb.x = f2bf(vb.x); sb.y = f2bf(vb.y); sb.z = f2bf(vb.z); sb.w = f2bf(vb.w);
            sc.x = f2bf(vc.x); sc.y = f2bf(vc.y); sc.z = f2bf(vc.z); sc.w = f2bf(vc.w);
            *(short4*)&Bb[row * LSTR + c0 + 4 * u] = sb;
            *(short4*)&Cc[row * LSTR + c0 + 4 * u] = sc;
        }
    }
    __syncthreads();
    // stage Xt (transposed, *dt) and BwT (transposed, *exp(Lc63-Lc_s))
    {
        int s = tid >> 2, c0 = (tid & 3) * 16;
        float w = dtv[s];
        float w2 = __expf(Lc[63] - Lc[s]);
        const float* pX = xBCc + (size_t)(m0 + s) * CONV_DIM + h * HEADDIM;
#pragma unroll
        for (int u = 0; u < 4; ++u) {
            f32x4 v = *(const f32x4*)(pX + c0 + 4 * u);
            Xt[(c0 + 4 * u + 0) * LSTR + s] = f2bf(v.x * w);
            Xt[(c0 + 4 * u + 1) * LSTR + s] = f2bf(v.y * w);
            Xt[(c0 + 4 * u + 2) * LSTR + s] = f2bf(v.z * w);
            Xt[(c0 + 4 * u + 3) * LSTR + s] = f2bf(v.w * w);
            short4 sb = *(short4*)&Bb[s * LSTR + c0 + 4 * u];
            BwT[(c0 + 4 * u + 0) * LSTR + s] = f2bf(bf2f(sb.x) * w2);
            BwT[(c0 + 4 * u + 1) * LSTR + s] = f2bf(bf2f(sb.y) * w2);
            BwT[(c0 + 4 * u + 2) * LSTR + s] = f2bf(bf2f(sb.z) * w2);
            BwT[(c0 + 4 * u + 3) * LSTR + s] = f2bf(bf2f(sb.w) * w2);
        }
    }
    __syncthreads();

    // G = C @ B^T (rows t = wid*16.., cols s), then masked/decayed M -> LDS
    {
        bf16x8 af[2];
#pragma unroll
        for (int kk = 0; kk < 2; ++kk)
            af[kk] = ld_frag(&Cc[(wid * 16 + lm) * LSTR + kk * 32 + lg * 8]);
#pragma unroll
        for (int j = 0; j < 4; ++j) {
            f32x4 acc = {0.f, 0.f, 0.f, 0.f};
#pragma unroll
            for (int kk = 0; kk < 2; ++kk) {
                bf16x8 bf = ld_frag(&Bb[(j * 16 + lm) * LSTR + kk * 32 + lg * 8]);
                acc = __builtin_amdgcn_mfma_f32_16x16x32_bf16(af[kk], bf, acc, 0, 0, 0);
            }
            int s = j * 16 + lm;
            float Ls = Lc[s];
#pragma unroll
            for (int r = 0; r < 4; ++r) {
                int t = wid * 16 + lg * 4 + r;
                float val = (s <= t) ? acc[r] * __expf(Lc[t] - Ls) : 0.f;
                Mm[t * LSTR + s] = f2bf(val);
            }
        }
    }
    __syncthreads();

    // Y1 = M @ X  and  S = BwT @ X   (B-operand = Xt for both)
    {
        bf16x8 am[2], aw[2];
#pragma unroll
        for (int kk = 0; kk < 2; ++kk) {
            am[kk] = ld_frag(&Mm[(wid * 16 + lm) * LSTR + kk * 32 + lg * 8]);
            aw[kk] = ld_frag(&BwT[(wid * 16 + lm) * LSTR + kk * 32 + lg * 8]);
        }
#pragma unroll
        for (int j = 0; j < 4; ++j) {
            f32x4 a1 = {0.f, 0.f, 0.f, 0.f};
            f32x4 a2 = {0.f, 0.f, 0.f, 0.f};
#pragma unroll
            for (int kk = 0; kk < 2; ++kk) {
                bf16x8 bx = ld_frag(&Xt[(j * 16 + lm) * LSTR + kk * 32 + lg * 8]);
                a1 = __builtin_amdgcn_mfma_f32_16x16x32_bf16(am[kk], bx, a1, 0, 0, 0);
                a2 = __builtin_amdgcn_mfma_f32_16x16x32_bf16(aw[kk], bx, a2, 0, 0, 0);
            }
            int p = j * 16 + lm;
#pragma unroll
            for (int r = 0; r < 4; ++r) {
                int t = wid * 16 + lg * 4 + r;   // row (= n for S)
                ybuf[(size_t)(m0 + t) * DIN + h * HEADDIM + p] = a1[r];
                Sbuf[(size_t)bid * 4096 + t * 64 + p] = a2[r];
            }
        }
    }
}

// ---------------- P2: inter-chunk state recurrence (in-place S -> H_in) ----------------
// grid = 64 blocks (b,h); sequential over 32 chunks; SH[bid_c] overwritten with H_in
__global__ __launch_bounds__(256) void state_kernel(
    float* __restrict__ SH, const float* __restrict__ cumdecay)
{
    int bh = blockIdx.x;
    int b = bh >> 5, h = bh & 31;
    int tid = threadIdx.x;
    f32x4 H[4];
#pragma unroll
    for (int u = 0; u < 4; ++u) H[u] = {0.f, 0.f, 0.f, 0.f};
    for (int c = 0; c < NCHUNK; ++c) {
        int cid = (b * NCHUNK + c) * NH + h;
        size_t base = (size_t)cid * 4096 + (size_t)tid * 16;
        float cd = cumdecay[(size_t)cid * 64 + 63];
        f32x4 s[4];
#pragma unroll
        for (int u = 0; u < 4; ++u) s[u] = *(const f32x4*)(SH + base + u * 4);
#pragma unroll
        for (int u = 0; u < 4; ++u) *(f32x4*)(SH + base + u * 4) = H[u];
#pragma unroll
        for (int u = 0; u < 4; ++u) {
            H[u].x = cd * H[u].x + s[u].x;
            H[u].y = cd * H[u].y + s[u].y;
            H[u].z = cd * H[u].z + s[u].z;
            H[u].w = cd * H[u].w + s[u].w;
        }
    }
}

// ---------------- P3: inter-chunk contribution y += exp(Lc_t) * C_t @ H_in ----------------
__global__ __launch_bounds__(256) void inter_kernel(
    const float* __restrict__ xBCc, const float* __restrict__ Hin,
    const float* __restrict__ cumdecay, float* __restrict__ ybuf)
{
    int bid = blockIdx.x;
    int h = bid & 31, c = (bid >> 5) & 31, b = bid >> 10;
    int m0 = b * SEQ + c * Q;
    int tid = threadIdx.x;
    int wid = tid >> 6, lane = tid & 63, lm = lane & 15, lg = lane >> 4;

    __shared__ short Cc[64 * LSTR];   // [t][n]
    __shared__ short HT[64 * LSTR];   // [p][n]
    __shared__ float eLc[64];

    if (tid < 64) eLc[tid] = cumdecay[(size_t)bid * 64 + tid];
    {
        int row = tid >> 2, c0 = (tid & 3) * 16;
        const float* pC = xBCc + (size_t)(m0 + row) * CONV_DIM + DIN + DSTATE;
        const float* pH = Hin + (size_t)bid * 4096 + row * 64;   // row = n
#pragma unroll
        for (int u = 0; u < 4; ++u) {
            f32x4 vc = *(const f32x4*)(pC + c0 + 4 * u);
            short4 sc;
            sc.x = f2bf(vc.x); sc.y = f2bf(vc.y); sc.z = f2bf(vc.z); sc.w = f2bf(vc.w);
            *(short4*)&Cc[row * LSTR + c0 + 4 * u] = sc;
            f32x4 vh = *(const f32x4*)(pH + c0 + 4 * u);
            HT[(c0 + 4 * u + 0) * LSTR + row] = f2bf(vh.x);
            HT[(c0 + 4 * u + 1) * LSTR + row] = f2bf(vh.y);
            HT[(c0 + 4 * u + 2) * LSTR + row] = f2bf(vh.z);
            HT[(c0 + 4 * u + 3) * LSTR + row] = f2bf(vh.w);
        }
    }
    __syncthreads();

    bf16x8 af[2];
#pragma unroll
    for (int kk = 0; kk < 2; ++kk)
        af[kk] = ld_frag(&Cc[(wid * 16 + lm) * LSTR + kk * 32 + lg * 8]);
#pragma unroll
    for (int j = 0; j < 4; ++j) {
        f32x4 acc = {0.f, 0.f, 0.f, 0.f};
#pragma unroll
        for (int kk = 0; kk < 2; ++kk) {
            bf16x8 bh_ = ld_frag(&HT[(j * 16 + lm) * LSTR + kk * 32 + lg * 8]);
            acc = __builtin_amdgcn_mfma_f32_16x16x32_bf16(af[kk], bh_, acc, 0, 0, 0);
        }
        int p = j * 16 + lm;
#pragma unroll
        for (int r = 0; r < 4; ++r) {
            int t = wid * 16 + lg * 4 + r;
            size_t ya = (size_t)(m0 + t) * DIN + h * HEADDIM + p;
            ybuf[ya] += eLc[t] * acc[r];
        }
    }
}

// ---------------- y = rmsnorm((y + D*x) * silu(z), norm_w), in-place ----------------
__global__ __launch_bounds__(256) void norm1_kernel(
    const float* __restrict__ zx, const float* __restrict__ xBCc,
    const float* __restrict__ Dp, float* __restrict__ y, const float* __restrict__ w)
{
    int m = blockIdx.x;
    int t = threadIdx.x;
    const float* zr = zx + (size_t)m * DPROJ;
    const float* xr = xBCc + (size_t)m * CONV_DIM;
    float* yr = y + (size_t)m * DIN;
    float vals[8];
    float ss = 0.f;
#pragma unroll
    for (int j = 0; j < 8; ++j) {
        int i = j * 256 + t;
        float v = (yr[i] + Dp[i >> 6] * xr[i]) * silu_f(zr[i]);
        vals[j] = v;
        ss += v * v;
    }
#pragma unroll
    for (int o = 32; o >= 1; o >>= 1) ss += __shfl_xor(ss, o);
    __shared__ float wsum[4];
    if ((t & 63) == 0) wsum[t >> 6] = ss;
    __syncthreads();
    float tot = wsum[0] + wsum[1] + wsum[2] + wsum[3];
    float scale = rsqrtf(tot / (float)DIN + EPS);
#pragma unroll
    for (int j = 0; j < 8; ++j) {
        int i = j * 256 + t;
        yr[i] = vals[j] * scale * w[i];
    }
}

// ---------------- hn = rmsnorm(h, rms_w) ----------------
__global__ __launch_bounds__(256) void norm2_kernel(
    const float* __restrict__ hb, float* __restrict__ hn, const float* __restrict__ w)
{
    int m = blockIdx.x;
    int t = threadIdx.x;
    const float* hr = hb + (size_t)m * DMODEL;
    float vals[4];
    float ss = 0.f;
#pragma unroll
    for (int j = 0; j < 4; ++j) {
        int i = j * 256 + t;
        float v = hr[i];
        vals[j] = v;
        ss += v * v;
    }
#pragma unroll
    for (int o = 32; o >= 1; o >>= 1) ss += __shfl_xor(ss, o);
    __shared__ float wsum[4];
    if ((t & 63) == 0) wsum[t >> 6] = ss;
    __syncthreads();
    float tot = wsum[0] + wsum[1] + wsum[2] + wsum[3];
    float scale = rsqrtf(tot / (float)DMODEL + EPS);
#pragma unroll
    for (int j = 0; j < 4; ++j) {
        int i = j * 256 + t;
        hn[(size_t)m * DMODEL + i] = vals[j] * scale * w[i];
    }
}

extern "C" void kernel_launch(void* const* d_in, const int* in_sizes, int n_in,
                              void* d_out, int out_size, void* d_ws, size_t ws_size,
                              hipStream_t stream) {
    const float* x       = (const float*)d_in[0];
    const float* W_in    = (const float*)d_in[1];
    const float* conv_w  = (const float*)d_in[2];
    const float* conv_b  = (const float*)d_in[3];
    const float* dt_bias = (const float*)d_in[4];
    const float* A_log   = (const float*)d_in[5];
    const float* D_param = (const float*)d_in[6];
    const float* norm_w  = (const float*)d_in[7];
    const float* W_out   = (const float*)d_in[8];
    const float* rms_w   = (const float*)d_in[9];
    const float* mlp_w1  = (const float*)d_in[10];
    const float* mlp_b1  = (const float*)d_in[11];
    const float* mlp_w2  = (const float*)d_in[12];
    const float* mlp_b2  = (const float*)d_in[13];
    float* out = (float*)d_out;

    float* ws       = (float*)d_ws;
    float* zx       = ws;                                 // TOKENS*DPROJ
    float* xBCc     = zx + (size_t)TOKENS * DPROJ;        // TOKENS*CONV_DIM
    float* dtb      = xBCc + (size_t)TOKENS * CONV_DIM;   // TOKENS*NH
    float* ldab     = dtb + (size_t)TOKENS * NH;          // TOKENS*NH
    float* cumdecay = ldab + (size_t)TOKENS * NH;         // TOKENS*NH (=NCH*64)
    float* ybuf     = cumdecay + (size_t)TOKENS * NH;     // TOKENS*DIN
    float* SH       = ybuf + (size_t)TOKENS * DIN;        // NCH*4096
    float* hbuf     = SH;                                 // alias (SH dead after P3-consumers)
    float* hnbuf    = SH + (size_t)TOKENS * DMODEL;       // alias upper half
    float* mid      = zx;                                 // reuse zx for MLP intermediate

    dim3 blk(256);

    // 1. zxbcdt = x @ W_in
    gemm_kernel<0><<<dim3((DPROJ + 127) / 128, TOKENS / 128), blk, 0, stream>>>(
        x, W_in, zx, nullptr, nullptr, TOKENS, DPROJ, DMODEL);
    // 2. conv + bias + silu
    conv_kernel<<<dim3(TOKENS, (CONV_DIM / 4 + 255) / 256), blk, 0, stream>>>(
        zx, conv_w, conv_b, xBCc);
    // 3. dt / ldA
    dt_kernel<<<dim3(TOKENS * NH / 256), blk, 0, stream>>>(zx, dt_bias, A_log, dtb, ldab);
    // 4a. intra-chunk SSD -> ybuf (intra), Sbuf, cumdecay
    chunk_kernel<<<dim3(NCH), blk, 0, stream>>>(xBCc, dtb, ldab, ybuf, SH, cumdecay);
    // 4b. inter-chunk state recurrence (in-place SH: S -> H_in)
    state_kernel<<<dim3(BATCH * NH), blk, 0, stream>>>(SH, cumdecay);
    // 4c. add inter-chunk contribution
    inter_kernel<<<dim3(NCH), blk, 0, stream>>>(xBCc, SH, cumdecay, ybuf);
    // 5. y = rmsnorm((y + D*x) * silu(z)) in place
    norm1_kernel<<<dim3(TOKENS), blk, 0, stream>>>(zx, xBCc, D_param, ybuf, norm_w);
    // 6. h = x + y @ W_out
    gemm_kernel<3><<<dim3(DMODEL / 128, TOKENS / 128), blk, 0, stream>>>(
        ybuf, W_out, hbuf, nullptr, x, TOKENS, DMODEL, DIN);
    // 7. hn = rmsnorm(h)
    norm2_kernel<<<dim3(TOKENS), blk, 0, stream>>>(hbuf, hnbuf, rms_w);
    // 8. mid = silu(hn @ mlp_w1 + b1)
    gemm_kernel<1><<<dim3(MLP_INNER / 128, TOKENS / 128), blk, 0, stream>>>(
        hnbuf, mlp_w1, mid, mlp_b1, nullptr, TOKENS, MLP_INNER, DMODEL);
    // 9. out = h + mid @ mlp_w2 + b2
    gemm_kernel<2><<<dim3(DMODEL / 128, TOKENS / 128), blk, 0, stream>>>(
        mid, mlp_w2, out, mlp_b2, hbuf, TOKENS, DMODEL, MLP_INNER);
}

// Round 3
// 561.961 us; speedup vs baseline: 3.2960x; 2.1632x over previous
//
#include <hip/hip_runtime.h>
#include <hip/hip_bf16.h>
#include <cstdint>
#include <cstddef>

#define BATCH 2
#define SEQ 2048
#define DMODEL 1024
#define DIN 2048
#define NH 32
#define HEADDIM 64
#define DSTATE 64
#define DCONV 4
#define CONV_DIM (DIN + 2 * DSTATE)          // 2176
#define DPROJ (2 * DIN + 2 * DSTATE + NH)    // 4256
#define MLP_INNER 4096
#define TOKENS (BATCH * SEQ)                 // 4096
#define EPS 1e-5f
#define Q 64
#define NCHUNK (SEQ / Q)                     // 32
#define NCH (BATCH * NCHUNK * NH)            // 2048 chunk-heads
#define LSTR 72
#define NPAD_IN 4352                          // DPROJ padded to 34*128

typedef __attribute__((ext_vector_type(8))) short short8;
typedef __attribute__((ext_vector_type(8))) __bf16 bf16x8;
typedef __attribute__((ext_vector_type(4))) float f32x4;

__device__ inline short f2bf(float f) {
    unsigned u = __builtin_bit_cast(unsigned, f);
    u = (u + 0x7FFFu + ((u >> 16) & 1u)) >> 16;
    return (short)u;
}
__device__ inline float bf2f(short s) {
    unsigned u = ((unsigned)(unsigned short)s) << 16;
    return __builtin_bit_cast(float, u);
}
__device__ inline float silu_f(float x) { return x / (1.f + __expf(-x)); }

__device__ inline bf16x8 ld_frag(const short* p) {
    short8 s = *(const short8*)p;
    return __builtin_bit_cast(bf16x8, s);
}

__device__ inline void glds16(const short* g, short* l) {
    __builtin_amdgcn_global_load_lds(
        (const __attribute__((address_space(1))) void*)g,
        (__attribute__((address_space(3))) void*)l, 16, 0, 0);
}

// ---------------- bf16 GEMM, m97 structure ----------------
// A: [M][K] bf16 row-major. BT: [Npad][K] bf16 (i.e. B transposed). BK=32, tile 128x128.
// MODE 0: f32 C = AB; 1: bf16 C = silu(AB+bias); 2: f32 C = AB+bias+res; 3: f32 C = AB+res
template <int MODE>
__global__ __launch_bounds__(256, 2) void gemm_bf16_kernel(
    const short* __restrict__ A, const short* __restrict__ BT,
    void* __restrict__ Cout, const float* __restrict__ bias,
    const float* __restrict__ res, int M, int N, int K)
{
    const int tid  = threadIdx.x;
    const int wid  = tid >> 6;
    const int lane = tid & 63;
    const int lm   = lane & 15;
    const int lg   = lane >> 4;
    const int m0   = blockIdx.y * 128;
    const int n0   = blockIdx.x * 128;

    __shared__ __attribute__((aligned(16))) short Al[128 * 32];  // [row][k] 64B rows, no pad
    __shared__ __attribute__((aligned(16))) short Bl[128 * 32];  // [n][k]

    f32x4 acc[4][4];
#pragma unroll
    for (int i = 0; i < 4; ++i)
#pragma unroll
        for (int j = 0; j < 4; ++j) acc[i][j] = {0.f, 0.f, 0.f, 0.f};

    const int wm = (wid >> 1) * 64;
    const int wn = (wid & 1) * 64;

    // staging: wave w covers rows [w*32, w*32+32); instr i handles 16 rows
    const int srow = lane >> 2;         // 0..15
    const int scol = (lane & 3) * 8;    // shorts (16B)
    const short* Ag = A  + (size_t)(m0 + wid * 32 + srow) * K + scol;
    const short* Bg = BT + (size_t)(n0 + wid * 32 + srow) * K + scol;
    short* Ald = &Al[wid * 1024];
    short* Bld = &Bl[wid * 1024];

    for (int kt = 0; kt < K; kt += 32) {
        glds16(Ag + kt,           Ald);
        glds16(Ag + 16 * K + kt,  Ald + 512);
        glds16(Bg + kt,           Bld);
        glds16(Bg + 16 * K + kt,  Bld + 512);
        __syncthreads();   // drains vmcnt: staged tile visible

        bf16x8 af[4], bf[4];
#pragma unroll
        for (int i = 0; i < 4; ++i)
            af[i] = ld_frag(&Al[(wm + i * 16 + lm) * 32 + lg * 8]);
#pragma unroll
        for (int j = 0; j < 4; ++j)
            bf[j] = ld_frag(&Bl[(wn + j * 16 + lm) * 32 + lg * 8]);
#pragma unroll
        for (int i = 0; i < 4; ++i)
#pragma unroll
            for (int j = 0; j < 4; ++j)
                acc[i][j] = __builtin_amdgcn_mfma_f32_16x16x32_bf16(af[i], bf[j], acc[i][j], 0, 0, 0);
        __syncthreads();   // all reads done before next overwrite
    }

#pragma unroll
    for (int i = 0; i < 4; ++i) {
#pragma unroll
        for (int j = 0; j < 4; ++j) {
            int col = n0 + wn + j * 16 + lm;
            if (col >= N) continue;
            float bv = (MODE == 1 || MODE == 2) ? bias[col] : 0.f;
#pragma unroll
            for (int r = 0; r < 4; ++r) {
                int row = m0 + wm + i * 16 + lg * 4 + r;
                float v = acc[i][j][r];
                if (MODE == 1) {
                    ((short*)Cout)[(size_t)row * N + col] = f2bf(silu_f(v + bv));
                } else {
                    if (MODE == 2) v = v + bv + res[(size_t)row * N + col];
                    if (MODE == 3) v = v + res[(size_t)row * N + col];
                    ((float*)Cout)[(size_t)row * N + col] = v;
                }
            }
        }
    }
}

// ---------------- f32 -> bf16 convert ----------------
__global__ __launch_bounds__(256) void cvt_kernel(
    const float* __restrict__ src, short* __restrict__ dst, int n4)
{
    int i = (blockIdx.x * 256 + threadIdx.x);
    if (i >= n4) return;
    f32x4 v = *(const f32x4*)(src + (size_t)i * 4);
    short4 o;
    o.x = f2bf(v.x); o.y = f2bf(v.y); o.z = f2bf(v.z); o.w = f2bf(v.w);
    *(short4*)(dst + (size_t)i * 4) = o;
}

// ---------------- W [K][N] f32 -> WT [Npad][K] bf16 (zero-fill pad rows) ----------------
__global__ __launch_bounds__(256) void transpose_kernel(
    const float* __restrict__ src, short* __restrict__ dst, int K, int N)
{
    __shared__ float t[32][33];
    int bx = blockIdx.x, by = blockIdx.y;
    int col = threadIdx.x & 31, row8 = threadIdx.x >> 5;
    int gn = bx * 32 + col;
#pragma unroll
    for (int r = 0; r < 4; ++r) {
        int gk = by * 32 + row8 + r * 8;
        t[row8 + r * 8][col] = (gn < N) ? src[(size_t)gk * N + gn] : 0.f;
    }
    __syncthreads();
#pragma unroll
    for (int r = 0; r < 4; ++r) {
        int n = bx * 32 + row8 + r * 8;
        dst[(size_t)n * K + by * 32 + col] = f2bf(t[col][row8 + r * 8]);
    }
}

// ---------------- depthwise causal conv (k=4) + bias + silu ----------------
__global__ __launch_bounds__(256) void conv_kernel(
    const float* __restrict__ zx, const float* __restrict__ cw,
    const float* __restrict__ cb, float* __restrict__ xBCc)
{
    int c4 = blockIdx.y * 256 + threadIdx.x;
    if (c4 >= CONV_DIM / 4) return;
    int m = blockIdx.x;
    int l = m & (SEQ - 1);
    int c = c4 * 4;
    const float* base = zx + (size_t)m * DPROJ + DIN + c;
    f32x4 acc = {0.f, 0.f, 0.f, 0.f};
#pragma unroll
    for (int j = 0; j < DCONV; ++j) {
        if (l - 3 + j < 0) continue;
        f32x4 xv = *(const f32x4*)(base + (ptrdiff_t)(j - 3) * DPROJ);
        acc.x += xv.x * cw[(c + 0) * DCONV + j];
        acc.y += xv.y * cw[(c + 1) * DCONV + j];
        acc.z += xv.z * cw[(c + 2) * DCONV + j];
        acc.w += xv.w * cw[(c + 3) * DCONV + j];
    }
    f32x4 o;
    o.x = silu_f(acc.x + cb[c + 0]);
    o.y = silu_f(acc.y + cb[c + 1]);
    o.z = silu_f(acc.z + cb[c + 2]);
    o.w = silu_f(acc.w + cb[c + 3]);
    *(f32x4*)(xBCc + (size_t)m * CONV_DIM + c) = o;
}

// ---------------- dt = softplus(dt_raw + bias); ldA = A * dt ----------------
__global__ __launch_bounds__(256) void dt_kernel(
    const float* __restrict__ zx, const float* __restrict__ dt_bias,
    const float* __restrict__ A_log, float* __restrict__ dtb, float* __restrict__ ldab)
{
    int idx = blockIdx.x * 256 + threadIdx.x;
    if (idx >= TOKENS * NH) return;
    int hh = idx & (NH - 1);
    int m  = idx >> 5;
    float v  = zx[(size_t)m * DPROJ + DIN + CONV_DIM + hh] + dt_bias[hh];
    float dt = (v > 20.f) ? v : log1pf(__expf(v));
    dtb[idx]  = dt;
    ldab[idx] = -__expf(A_log[hh]) * dt;
}

// ---------------- P1: intra-chunk SSD ----------------
__global__ __launch_bounds__(256) void chunk_kernel(
    const float* __restrict__ xBCc, const float* __restrict__ dtb,
    const float* __restrict__ ldab, float* __restrict__ ybuf,
    float* __restrict__ Sbuf, float* __restrict__ cumdecay)
{
    int bid = blockIdx.x;
    int h = bid & 31, c = (bid >> 5) & 31, b = bid >> 10;
    int m0 = b * SEQ + c * Q;
    int tid = threadIdx.x;
    int wid = tid >> 6, lane = tid & 63, lm = lane & 15, lg = lane >> 4;

    __shared__ __attribute__((aligned(16))) short Cc[64 * LSTR];
    __shared__ __attribute__((aligned(16))) short Bb[64 * LSTR];
    __shared__ __attribute__((aligned(16))) short BwT[64 * LSTR];
    __shared__ __attribute__((aligned(16))) short Xt[64 * LSTR];
    __shared__ __attribute__((aligned(16))) short Mm[64 * LSTR];
    __shared__ float Lc[64], dtv[64];

    if (tid < 64) {
        int s = tid;
        size_t ix = (size_t)(m0 + s) * NH + h;
        float ld = ldab[ix];
        float dt = dtb[ix];
        float v = ld;
#pragma unroll
        for (int off = 1; off < 64; off <<= 1) {
            float o = __shfl_up(v, off);
            if (s >= off) v += o;
        }
        Lc[s] = v;
        dtv[s] = dt;
        cumdecay[(size_t)bid * 64 + s] = __expf(v);
    }
    {
        int row = tid >> 2, c0 = (tid & 3) * 16;
        const float* pB = xBCc + (size_t)(m0 + row) * CONV_DIM + DIN;
#pragma unroll
        for (int u = 0; u < 4; ++u) {
            f32x4 vb = *(const f32x4*)(pB + c0 + 4 * u);
            f32x4 vc = *(const f32x4*)(pB + DSTATE + c0 + 4 * u);
            short4 sb, sc;
            sb.x = f2bf(vb.x); sb.y = f2bf(vb.y); sb.z = f2bf(vb.z); sb.w = f2bf(vb.w);
            sc.x = f2bf(vc.x); sc.y = f2bf(vc.y); sc.z = f2bf(vc.z); sc.w = f2bf(vc.w);
            *(short4*)&Bb[row * LSTR + c0 + 4 * u] = sb;
            *(short4*)&Cc[row * LSTR + c0 + 4 * u] = sc;
        }
    }
    __syncthreads();
    {
        int s = tid >> 2, c0 = (tid & 3) * 16;
        float w = dtv[s];
        float w2 = __expf(Lc[63] - Lc[s]);
        const float* pX = xBCc + (size_t)(m0 + s) * CONV_DIM + h * HEADDIM;
#pragma unroll
        for (int u = 0; u < 4; ++u) {
            f32x4 v = *(const f32x4*)(pX + c0 + 4 * u);
            Xt[(c0 + 4 * u + 0) * LSTR + s] = f2bf(v.x * w);
            Xt[(c0 + 4 * u + 1) * LSTR + s] = f2bf(v.y * w);
            Xt[(c0 + 4 * u + 2) * LSTR + s] = f2bf(v.z * w);
            Xt[(c0 + 4 * u + 3) * LSTR + s] = f2bf(v.w * w);
            short4 sb = *(short4*)&Bb[s * LSTR + c0 + 4 * u];
            BwT[(c0 + 4 * u + 0) * LSTR + s] = f2bf(bf2f(sb.x) * w2);
            BwT[(c0 + 4 * u + 1) * LSTR + s] = f2bf(bf2f(sb.y) * w2);
            BwT[(c0 + 4 * u + 2) * LSTR + s] = f2bf(bf2f(sb.z) * w2);
            BwT[(c0 + 4 * u + 3) * LSTR + s] = f2bf(bf2f(sb.w) * w2);
        }
    }
    __syncthreads();

    {
        bf16x8 af[2];
#pragma unroll
        for (int kk = 0; kk < 2; ++kk)
            af[kk] = ld_frag(&Cc[(wid * 16 + lm) * LSTR + kk * 32 + lg * 8]);
#pragma unroll
        for (int j = 0; j < 4; ++j) {
            f32x4 acc = {0.f, 0.f, 0.f, 0.f};
#pragma unroll
            for (int kk = 0; kk < 2; ++kk) {
                bf16x8 bf = ld_frag(&Bb[(j * 16 + lm) * LSTR + kk * 32 + lg * 8]);
                acc = __builtin_amdgcn_mfma_f32_16x16x32_bf16(af[kk], bf, acc, 0, 0, 0);
            }
            int s = j * 16 + lm;
            float Ls = Lc[s];
#pragma unroll
            for (int r = 0; r < 4; ++r) {
                int t = wid * 16 + lg * 4 + r;
                float val = (s <= t) ? acc[r] * __expf(Lc[t] - Ls) : 0.f;
                Mm[t * LSTR + s] = f2bf(val);
            }
        }
    }
    __syncthreads();

    {
        bf16x8 am[2], aw[2];
#pragma unroll
        for (int kk = 0; kk < 2; ++kk) {
            am[kk] = ld_frag(&Mm[(wid * 16 + lm) * LSTR + kk * 32 + lg * 8]);
            aw[kk] = ld_frag(&BwT[(wid * 16 + lm) * LSTR + kk * 32 + lg * 8]);
        }
#pragma unroll
        for (int j = 0; j < 4; ++j) {
            f32x4 a1 = {0.f, 0.f, 0.f, 0.f};
            f32x4 a2 = {0.f, 0.f, 0.f, 0.f};
#pragma unroll
            for (int kk = 0; kk < 2; ++kk) {
                bf16x8 bx = ld_frag(&Xt[(j * 16 + lm) * LSTR + kk * 32 + lg * 8]);
                a1 = __builtin_amdgcn_mfma_f32_16x16x32_bf16(am[kk], bx, a1, 0, 0, 0);
                a2 = __builtin_amdgcn_mfma_f32_16x16x32_bf16(aw[kk], bx, a2, 0, 0, 0);
            }
            int p = j * 16 + lm;
#pragma unroll
            for (int r = 0; r < 4; ++r) {
                int t = wid * 16 + lg * 4 + r;
                ybuf[(size_t)(m0 + t) * DIN + h * HEADDIM + p] = a1[r];
                Sbuf[(size_t)bid * 4096 + t * 64 + p] = a2[r];
            }
        }
    }
}

// ---------------- P2: inter-chunk state recurrence ----------------
__global__ __launch_bounds__(256) void state_kernel(
    float* __restrict__ SH, const float* __restrict__ cumdecay)
{
    int bh = blockIdx.x;
    int b = bh >> 5, h = bh & 31;
    int tid = threadIdx.x;
    f32x4 H[4];
#pragma unroll
    for (int u = 0; u < 4; ++u) H[u] = {0.f, 0.f, 0.f, 0.f};
    for (int c = 0; c < NCHUNK; ++c) {
        int cid = (b * NCHUNK + c) * NH + h;
        size_t base = (size_t)cid * 4096 + (size_t)tid * 16;
        float cd = cumdecay[(size_t)cid * 64 + 63];
        f32x4 s[4];
#pragma unroll
        for (int u = 0; u < 4; ++u) s[u] = *(const f32x4*)(SH + base + u * 4);
#pragma unroll
        for (int u = 0; u < 4; ++u) *(f32x4*)(SH + base + u * 4) = H[u];
#pragma unroll
        for (int u = 0; u < 4; ++u) {
            H[u].x = cd * H[u].x + s[u].x;
            H[u].y = cd * H[u].y + s[u].y;
            H[u].z = cd * H[u].z + s[u].z;
            H[u].w = cd * H[u].w + s[u].w;
        }
    }
}

// ---------------- P3: y += exp(Lc_t) * C_t @ H_in ----------------
__global__ __launch_bounds__(256) void inter_kernel(
    const float* __restrict__ xBCc, const float* __restrict__ Hin,
    const float* __restrict__ cumdecay, float* __restrict__ ybuf)
{
    int bid = blockIdx.x;
    int h = bid & 31, c = (bid >> 5) & 31, b = bid >> 10;
    int m0 = b * SEQ + c * Q;
    int tid = threadIdx.x;
    int wid = tid >> 6, lane = tid & 63, lm = lane & 15, lg = lane >> 4;

    __shared__ __attribute__((aligned(16))) short Cc[64 * LSTR];
    __shared__ __attribute__((aligned(16))) short HT[64 * LSTR];
    __shared__ float eLc[64];

    if (tid < 64) eLc[tid] = cumdecay[(size_t)bid * 64 + tid];
    {
        int row = tid >> 2, c0 = (tid & 3) * 16;
        const float* pC = xBCc + (size_t)(m0 + row) * CONV_DIM + DIN + DSTATE;
        const float* pH = Hin + (size_t)bid * 4096 + row * 64;
#pragma unroll
        for (int u = 0; u < 4; ++u) {
            f32x4 vc = *(const f32x4*)(pC + c0 + 4 * u);
            short4 sc;
            sc.x = f2bf(vc.x); sc.y = f2bf(vc.y); sc.z = f2bf(vc.z); sc.w = f2bf(vc.w);
            *(short4*)&Cc[row * LSTR + c0 + 4 * u] = sc;
            f32x4 vh = *(const f32x4*)(pH + c0 + 4 * u);
            HT[(c0 + 4 * u + 0) * LSTR + row] = f2bf(vh.x);
            HT[(c0 + 4 * u + 1) * LSTR + row] = f2bf(vh.y);
            HT[(c0 + 4 * u + 2) * LSTR + row] = f2bf(vh.z);
            HT[(c0 + 4 * u + 3) * LSTR + row] = f2bf(vh.w);
        }
    }
    __syncthreads();

    bf16x8 af[2];
#pragma unroll
    for (int kk = 0; kk < 2; ++kk)
        af[kk] = ld_frag(&Cc[(wid * 16 + lm) * LSTR + kk * 32 + lg * 8]);
#pragma unroll
    for (int j = 0; j < 4; ++j) {
        f32x4 acc = {0.f, 0.f, 0.f, 0.f};
#pragma unroll
        for (int kk = 0; kk < 2; ++kk) {
            bf16x8 bh_ = ld_frag(&HT[(j * 16 + lm) * LSTR + kk * 32 + lg * 8]);
            acc = __builtin_amdgcn_mfma_f32_16x16x32_bf16(af[kk], bh_, acc, 0, 0, 0);
        }
        int p = j * 16 + lm;
#pragma unroll
        for (int r = 0; r < 4; ++r) {
            int t = wid * 16 + lg * 4 + r;
            size_t ya = (size_t)(m0 + t) * DIN + h * HEADDIM + p;
            ybuf[ya] += eLc[t] * acc[r];
        }
    }
}

// ---------------- ybf = bf16(rmsnorm((y + D*x) * silu(z), norm_w)) ----------------
__global__ __launch_bounds__(256) void norm1_kernel(
    const float* __restrict__ zx, const float* __restrict__ xBCc,
    const float* __restrict__ Dp, const float* __restrict__ y,
    short* __restrict__ ybf, const float* __restrict__ w)
{
    int m = blockIdx.x;
    int t = threadIdx.x;
    const float* zr = zx + (size_t)m * DPROJ;
    const float* xr = xBCc + (size_t)m * CONV_DIM;
    const float* yr = y + (size_t)m * DIN;
    float vals[8];
    float ss = 0.f;
#pragma unroll
    for (int j = 0; j < 8; ++j) {
        int i = j * 256 + t;
        float v = (yr[i] + Dp[i >> 6] * xr[i]) * silu_f(zr[i]);
        vals[j] = v;
        ss += v * v;
    }
#pragma unroll
    for (int o = 32; o >= 1; o >>= 1) ss += __shfl_xor(ss, o);
    __shared__ float wsum[4];
    if ((t & 63) == 0) wsum[t >> 6] = ss;
    __syncthreads();
    float tot = wsum[0] + wsum[1] + wsum[2] + wsum[3];
    float scale = rsqrtf(tot / (float)DIN + EPS);
#pragma unroll
    for (int j = 0; j < 8; ++j) {
        int i = j * 256 + t;
        ybf[(size_t)m * DIN + i] = f2bf(vals[j] * scale * w[i]);
    }
}

// ---------------- hnbf = bf16(rmsnorm(h, rms_w)) ----------------
__global__ __launch_bounds__(256) void norm2_kernel(
    const float* __restrict__ hb, short* __restrict__ hnbf, const float* __restrict__ w)
{
    int m = blockIdx.x;
    int t = threadIdx.x;
    const float* hr = hb + (size_t)m * DMODEL;
    float vals[4];
    float ss = 0.f;
#pragma unroll
    for (int j = 0; j < 4; ++j) {
        int i = j * 256 + t;
        float v = hr[i];
        vals[j] = v;
        ss += v * v;
    }
#pragma unroll
    for (int o = 32; o >= 1; o >>= 1) ss += __shfl_xor(ss, o);
    __shared__ float wsum[4];
    if ((t & 63) == 0) wsum[t >> 6] = ss;
    __syncthreads();
    float tot = wsum[0] + wsum[1] + wsum[2] + wsum[3];
    float scale = rsqrtf(tot / (float)DMODEL + EPS);
#pragma unroll
    for (int j = 0; j < 4; ++j) {
        int i = j * 256 + t;
        hnbf[(size_t)m * DMODEL + i] = f2bf(vals[j] * scale * w[i]);
    }
}

extern "C" void kernel_launch(void* const* d_in, const int* in_sizes, int n_in,
                              void* d_out, int out_size, void* d_ws, size_t ws_size,
                              hipStream_t stream) {
    const float* x       = (const float*)d_in[0];
    const float* W_in    = (const float*)d_in[1];
    const float* conv_w  = (const float*)d_in[2];
    const float* conv_b  = (const float*)d_in[3];
    const float* dt_bias = (const float*)d_in[4];
    const float* A_log   = (const float*)d_in[5];
    const float* D_param = (const float*)d_in[6];
    const float* norm_w  = (const float*)d_in[7];
    const float* W_out   = (const float*)d_in[8];
    const float* rms_w   = (const float*)d_in[9];
    const float* mlp_w1  = (const float*)d_in[10];
    const float* mlp_b1  = (const float*)d_in[11];
    const float* mlp_w2  = (const float*)d_in[12];
    const float* mlp_b2  = (const float*)d_in[13];
    float* out = (float*)d_out;

    float* ws       = (float*)d_ws;
    float* zx       = ws;                                  // 17,432,576 f32
    float* xBCc     = zx + (size_t)TOKENS * DPROJ;         //  8,912,896 f32
    float* dtb      = xBCc + (size_t)TOKENS * CONV_DIM;
    float* ldab     = dtb + (size_t)TOKENS * NH;
    float* cumdecay = ldab + (size_t)TOKENS * NH;
    float* ybuf     = cumdecay + (size_t)TOKENS * NH;      //  8,388,608 f32 (xbf/midbf alias)
    float* SH       = ybuf + (size_t)TOKENS * DIN;         //  8,388,608 f32 (hbuf/hnbf alias)
    float* bfarea   = SH + (size_t)NCH * 4096;

    // aliases (lifetimes are disjoint):
    short* xbf   = (short*)ybuf;                           // used only in GEMM1 (before chunk)
    short* midbf = (short*)ybuf;                           // used after norm1 (ybuf f32 dead)
    float* hbuf  = SH;                                     // SH dead after inter_kernel
    short* hnbf  = (short*)(SH + (size_t)TOKENS * DMODEL); // upper half of SH region

    short* ybf   = (short*)bfarea;                                   // 8,388,608 sh
    short* WinT  = ybf + (size_t)TOKENS * DIN;                       // 4352*1024 sh
    short* WoutT = WinT + (size_t)NPAD_IN * DMODEL;                  // 1024*2048 sh
    short* w1T   = WoutT + (size_t)DMODEL * DIN;                     // 4096*1024 sh
    short* w2T   = w1T + (size_t)MLP_INNER * DMODEL;                 // 1024*4096 sh

    dim3 blk(256);

    // 0. conversions / weight transposes
    cvt_kernel<<<dim3(TOKENS * DMODEL / 4 / 256), blk, 0, stream>>>(x, xbf, TOKENS * DMODEL / 4);
    transpose_kernel<<<dim3(NPAD_IN / 32, DMODEL / 32), blk, 0, stream>>>(W_in, WinT, DMODEL, DPROJ);
    transpose_kernel<<<dim3(DMODEL / 32, DIN / 32), blk, 0, stream>>>(W_out, WoutT, DIN, DMODEL);
    transpose_kernel<<<dim3(MLP_INNER / 32, DMODEL / 32), blk, 0, stream>>>(mlp_w1, w1T, DMODEL, MLP_INNER);
    transpose_kernel<<<dim3(DMODEL / 32, MLP_INNER / 32), blk, 0, stream>>>(mlp_w2, w2T, MLP_INNER, DMODEL);

    // 1. zx = x @ W_in
    gemm_bf16_kernel<0><<<dim3(NPAD_IN / 128, TOKENS / 128), blk, 0, stream>>>(
        xbf, WinT, zx, nullptr, nullptr, TOKENS, DPROJ, DMODEL);
    // 2. conv + bias + silu
    conv_kernel<<<dim3(TOKENS, (CONV_DIM / 4 + 255) / 256), blk, 0, stream>>>(
        zx, conv_w, conv_b, xBCc);
    // 3. dt / ldA
    dt_kernel<<<dim3(TOKENS * NH / 256), blk, 0, stream>>>(zx, dt_bias, A_log, dtb, ldab);
    // 4. SSD
    chunk_kernel<<<dim3(NCH), blk, 0, stream>>>(xBCc, dtb, ldab, ybuf, SH, cumdecay);
    state_kernel<<<dim3(BATCH * NH), blk, 0, stream>>>(SH, cumdecay);
    inter_kernel<<<dim3(NCH), blk, 0, stream>>>(xBCc, SH, cumdecay, ybuf);
    // 5. ybf = bf16(rmsnorm((y + D*x) * silu(z)))
    norm1_kernel<<<dim3(TOKENS), blk, 0, stream>>>(zx, xBCc, D_param, ybuf, ybf, norm_w);
    // 6. h = x + ybf @ W_out
    gemm_bf16_kernel<3><<<dim3(DMODEL / 128, TOKENS / 128), blk, 0, stream>>>(
        ybf, WoutT, hbuf, nullptr, x, TOKENS, DMODEL, DIN);
    // 7. hnbf = bf16(rmsnorm(h))
    norm2_kernel<<<dim3(TOKENS), blk, 0, stream>>>(hbuf, hnbf, rms_w);
    // 8. midbf = bf16(silu(hnbf @ mlp_w1 + b1))
    gemm_bf16_kernel<1><<<dim3(MLP_INNER / 128, TOKENS / 128), blk, 0, stream>>>(
        hnbf, w1T, midbf, mlp_b1, nullptr, TOKENS, MLP_INNER, DMODEL);
    // 9. out = h + midbf @ mlp_w2 + b2
    gemm_bf16_kernel<2><<<dim3(DMODEL / 128, TOKENS / 128), blk, 0, stream>>>(
        midbf, w2T, out, mlp_b2, hbuf, TOKENS, DMODEL, MLP_INNER);
}